// Round 19
// baseline (2176.704 us; speedup 1.0000x reference)
//
#include <hip/hip_runtime.h>
#include <hip/hip_fp16.h>
#include <cstdint>
#include <cstddef>

#define T_STEPS 512
#define ROWSP   516          // padded rows per element (3-deep unconditional prefetch)
#define HID 40
#define GATES 120

typedef _Float16 half8 __attribute__((ext_vector_type(8)));
typedef _Float16 fp16x2 __attribute__((ext_vector_type(2)));
typedef float f32x4 __attribute__((ext_vector_type(4)));

__device__ __forceinline__ void wavesync() { asm volatile("s_waitcnt lgkmcnt(0)" ::: "memory"); }
__device__ __forceinline__ float bperm(int srclane, float v) {
    return __int_as_float(__builtin_amdgcn_ds_bpermute(srclane << 2, __float_as_int(v)));
}
__device__ __forceinline__ float sigm(float x) { return 1.f / (1.f + __expf(-x)); }

template<int J>
__device__ __forceinline__ fp16x2 ext2(half8 v) {
    return __builtin_shufflevector(v, v, 2 * J, 2 * J + 1);
}

// padded-row byte mapping: row i (linear e*512+t) lives at (e*516+t)*GATES
__device__ __forceinline__ size_t rowoff(int row) {
    return ((size_t)(row >> 9) * ROWSP + (row & 511)) * GATES;
}

// ---------------- weight prep (run once, tiny) ----------------
__global__ __launch_bounds__(256) void prep_pad(
    const float* __restrict__ w, const float* __restrict__ b,
    __half* __restrict__ out, int N, int K, int KPAD)
{
    const int idx = blockIdx.x * 256 + threadIdx.x;
    const int n = idx / KPAD, k = idx - n * KPAD;
    float v = 0.f;
    if (n < N) {
        if (k < K) v = w[n * K + k];
        else if (k == KPAD - 1) v = b[n];
    }
    out[idx] = __float2half(v);
}

__global__ __launch_bounds__(256) void prep_eff(
    const float* __restrict__ g_wih, const float* __restrict__ g_bih,
    const float* __restrict__ w2, const float* __restrict__ b2,
    __half* __restrict__ out)
{
    const int li  = blockIdx.y;
    const int idx = blockIdx.x * 256 + threadIdx.x;   // over 128*64
    const int n = idx >> 6, k = idx & 63;
    float v = 0.f;
    if (n < GATES) {
        const float* wrow = g_wih + ((size_t)(li + 1) * GATES + n) * HID;
        if (k < HID) {
            for (int j = 0; j < HID; ++j) v += wrow[j] * w2[((size_t)li * HID + j) * HID + k];
        } else if (k == 63) {
            v = g_bih[(size_t)(li + 1) * GATES + n];
            for (int j = 0; j < HID; ++j) v += wrow[j] * b2[(size_t)li * HID + j];
        }
    }
    out[(size_t)li * 128 * 64 + idx] = __float2half(v);
}

// ---------------- MFMA gate precompute (R7-verified; padded-row addressing) ----------------
template<int MODE>
__global__ __launch_bounds__(256) void precomp_mfma(
    const void* in_, _Float16* xp,
    const _Float16* __restrict__ wihpad,  // [128][KP]
    const _Float16* __restrict__ w1pad,   // [48][64] (MODE 2 only)
    int nrows)
{
    __shared__ _Float16 s_v[4][1024];     // per-wave 2KB swizzled V tile [16][64]
    const int tid  = threadIdx.x;
    const int wid  = tid >> 6, lane = tid & 63;
    const int g    = lane >> 4, r = lane & 15;

    constexpr int KP  = (MODE == 0) ? 32 : 64;
    constexpr int NKS = KP / 32;

    half8 bw[8][NKS];
    #pragma unroll
    for (int t = 0; t < 8; ++t)
        #pragma unroll
        for (int ks = 0; ks < NKS; ++ks)
            bw[t][ks] = *reinterpret_cast<const half8*>(wihpad + (t * 16 + r) * KP + ks * 32 + g * 8);

    half8 b1f[3][2];
    char* myv = nullptr;
    if constexpr (MODE == 2) {
        #pragma unroll
        for (int t = 0; t < 3; ++t)
            #pragma unroll
            for (int ks = 0; ks < 2; ++ks)
                b1f[t][ks] = *reinterpret_cast<const half8*>(w1pad + (t * 16 + r) * 64 + ks * 32 + g * 8);
        myv = (char*)&s_v[wid][0];
        uint4 z; z.x = z.y = z.z = z.w = 0u;
        *reinterpret_cast<uint4*>(myv + lane * 32)      = z;
        *reinterpret_cast<uint4*>(myv + lane * 32 + 16) = z;
        wavesync();
        if (lane < 16)
            *reinterpret_cast<_Float16*>(myv + lane * 128 + (126 ^ ((lane & 7) << 4))) = (_Float16)1.f;
        wavesync();
    }

    const int w0     = blockIdx.x * 4 + wid;
    const int stride = gridDim.x * 64;

    for (int rb = w0 * 16; rb < nrows; rb += stride) {
        half8 a0, a1;
        if constexpr (MODE == 0) {
            const float* xr = (const float*)in_ + (size_t)(rb + r) * 20;
            if (g < 2) {
                const float4 v0 = *reinterpret_cast<const float4*>(xr + g * 8);
                const float4 v1 = *reinterpret_cast<const float4*>(xr + g * 8 + 4);
                a0[0]=(_Float16)v0.x; a0[1]=(_Float16)v0.y; a0[2]=(_Float16)v0.z; a0[3]=(_Float16)v0.w;
                a0[4]=(_Float16)v1.x; a0[5]=(_Float16)v1.y; a0[6]=(_Float16)v1.z; a0[7]=(_Float16)v1.w;
            } else if (g == 2) {
                const float4 v0 = *reinterpret_cast<const float4*>(xr + 16);
                a0[0]=(_Float16)v0.x; a0[1]=(_Float16)v0.y; a0[2]=(_Float16)v0.z; a0[3]=(_Float16)v0.w;
                a0[4]=(_Float16)0.f; a0[5]=(_Float16)0.f; a0[6]=(_Float16)0.f; a0[7]=(_Float16)0.f;
            } else {
                #pragma unroll
                for (int j = 0; j < 8; ++j) a0[j] = (_Float16)0.f;
                a0[7] = (_Float16)1.f;    // bias slot k=31
            }
        } else {
            const _Float16* hr = (const _Float16*)in_ + rowoff(rb + r);
            a0 = *reinterpret_cast<const half8*>(hr + g * 8);          // k 0..31
            if (g == 0) {
                a1 = *reinterpret_cast<const half8*>(hr + 32);         // k 32..39
            } else {
                #pragma unroll
                for (int j = 0; j < 8; ++j) a1[j] = (_Float16)0.f;
                if (g == 3) a1[7] = (_Float16)1.f;                     // bias slot k=63
            }
        }

        if constexpr (MODE == 2) {
            #pragma unroll
            for (int t = 0; t < 3; ++t) {
                f32x4 acc = {0.f, 0.f, 0.f, 0.f};
                acc = __builtin_amdgcn_mfma_f32_16x16x32_f16(a0, b1f[t][0], acc, 0, 0, 0);
                acc = __builtin_amdgcn_mfma_f32_16x16x32_f16(a1, b1f[t][1], acc, 0, 0, 0);
                const int n2 = (t * 16 + r) * 2;                       // byte col
                #pragma unroll
                for (int reg = 0; reg < 4; ++reg) {
                    const int m = g * 4 + reg;
                    float v = acc[reg];
                    v = v > 0.f ? v : 0.01f * v;
                    *reinterpret_cast<_Float16*>(myv + m * 128 + (n2 ^ ((m & 7) << 4))) = (_Float16)v;
                }
            }
            wavesync();
            const int sw = (r & 7) << 4;
            a0 = *reinterpret_cast<const half8*>(myv + r * 128 + ((g * 16) ^ sw));
            a1 = *reinterpret_cast<const half8*>(myv + r * 128 + ((64 + g * 16) ^ sw));
        }

        #pragma unroll
        for (int t = 0; t < 8; ++t) {
            f32x4 acc = {0.f, 0.f, 0.f, 0.f};
            acc = __builtin_amdgcn_mfma_f32_16x16x32_f16(a0, bw[t][0], acc, 0, 0, 0);
            if constexpr (NKS == 2)
                acc = __builtin_amdgcn_mfma_f32_16x16x32_f16(a1, bw[t][1], acc, 0, 0, 0);
            const int n = t * 16 + r;
            if (n < GATES) {
                #pragma unroll
                for (int reg = 0; reg < 4; ++reg) {
                    const int m = g * 4 + reg;
                    xp[rowoff(rb + m) + n] = (_Float16)acc[reg];
                }
            }
        }
    }
}

// ---------------- recurrence: SGPR h-broadcast via v_readlane, f32 weights ----------------
// After activation, lane l holds h_l. 40 readlanes (imm lane idx, exec-independent)
// place the whole h vector in wave-uniform regs; the h-dot becomes 80 f32 FMAs
// with uniform src — NO s_h buffer, NO LDS round-trip, loop LDS = 2 bperms only.
// Weights: whh f32 LDS-staged -> 80 resident VGPRs (R16-proven pinning: budget
// attr + loop-end wavesync clobber). Full-f32 h path (precision up vs f16).
__global__ __launch_bounds__(64)
__attribute__((amdgpu_waves_per_eu(2, 2)))
void gru_recS(
    __half* __restrict__ xp,          // [CB, ROWSP, 120], h written into [t][0:40]
    const float* __restrict__ whh,    // [120][40] f32 (original input weights)
    const float* __restrict__ bhh)    // [120]
{
    __shared__ __align__(16) float s_w[GATES * HID];  // 19200 B staging

    const int lane = threadIdx.x;
    const int e    = blockIdx.x;

    for (int idx = lane; idx < (GATES * HID) / 4; idx += 64)
        reinterpret_cast<uint4*>(s_w)[idx] = reinterpret_cast<const uint4*>(whh)[idx];

    const int gA = lane;
    const int gB = (lane < 40) ? (80 + lane) : ((lane < 56) ? (24 + lane) : lane);
    const float bhA = bhh[gA], bhB = bhh[gB];

    __half* xpb = xp + (size_t)e * ROWSP * GATES;
    wavesync();   // staging visible

    float wA[40], wB[40];
    #pragma unroll
    for (int k = 0; k < 10; ++k) {
        reinterpret_cast<float4*>(wA)[k] = *reinterpret_cast<const float4*>(s_w + gA * HID + 4 * k);
        reinterpret_cast<float4*>(wB)[k] = *reinterpret_cast<const float4*>(s_w + gB * HID + 4 * k);
    }
    wavesync();

    float hreg = 0.f;
    float hb[40];
    #pragma unroll
    for (int j = 0; j < 40; ++j) hb[j] = 0.f;

    // 3-deep prefetch, pointer-bumped; padded rows make it unconditional
    __half a0 = xpb[gA],             c0 = xpb[gB];
    __half a1 = xpb[GATES + gA],     c1 = xpb[GATES + gB];
    __half a2 = xpb[2 * GATES + gA], c2 = xpb[2 * GATES + gB];
    const __half* pfA = xpb + 3 * GATES + gA;
    const __half* pfB = xpb + 3 * GATES + gB;
    __half*       pst = xpb + lane;

    #pragma unroll 2
    for (int t = 0; t < T_STEPS; ++t) {
        const __half a3 = *pfA;  pfA += GATES;
        const __half c3 = *pfB;  pfB += GATES;

        // h-dot: 8 independent FMA chains, h operands wave-uniform (SGPR)
        float A0 = 0.f, A1 = 0.f, A2 = 0.f, A3 = 0.f;
        float B0 = 0.f, B1 = 0.f, B2 = 0.f, B3 = 0.f;
        #pragma unroll
        for (int k = 0; k < 40; k += 4) {
            A0 += hb[k+0] * wA[k+0];  B0 += hb[k+0] * wB[k+0];
            A1 += hb[k+1] * wA[k+1];  B1 += hb[k+1] * wB[k+1];
            A2 += hb[k+2] * wA[k+2];  B2 += hb[k+2] * wB[k+2];
            A3 += hb[k+3] * wA[k+3];  B3 += hb[k+3] * wB[k+3];
        }
        const float shA = bhA + ((A0 + A2) + (A1 + A3));
        const float shB = bhB + ((B0 + B2) + (B1 + B3));
        const float xA  = __half2float(a0);
        const float xB  = __half2float(c0);
        const float sumA = xA + shA;
        const float sumB = xB + shB;
        // z_l: lane 40+l (sumA) for l<24, lane 16+l (sumB) for l>=24. All lanes execute.
        const float zA = bperm(40 + lane, sumA);
        const float zB = bperm(16 + lane, sumB);

        // activation branch-free (lanes>=40 produce garbage, never read back)
        const float rr  = sigm(sumA);
        const float z   = sigm((lane < 24) ? zA : zB);
        const float pre = xB + rr * shB;          // x_n + r*h_n (biases included)
        const float ex  = __expf(-2.f * pre);
        const float nn  = (1.f - ex) / (1.f + ex);
        hreg = (1.f - z) * nn + z * hreg;

        // SGPR broadcast of h (readlane ignores exec; lanes 0..39 hold valid h)
        const int hi = __float_as_int(hreg);
        #pragma unroll
        for (int j = 0; j < 40; ++j)
            hb[j] = __int_as_float(__builtin_amdgcn_readlane(hi, j));

        if (lane < HID) *pst = __float2half(hreg);
        pst += GATES;

        a0 = a1; c0 = c1; a1 = a2; c1 = c2; a2 = a3; c2 = c3;
        wavesync();   // ~free (bperms drained); keeps weight regs pinned (R16 mechanism)
    }
}

// ---------------- head ----------------
__global__ __launch_bounds__(256) void final_head(
    const __half* __restrict__ xpbuf,  // padded buffer base
    float* __restrict__ outp,          // [CB]
    const float* __restrict__ w1, const float* __restrict__ b1,
    const float* __restrict__ wl, const float* __restrict__ bl, int n)
{
    __shared__ float s_w1[HID][HID + 1];
    __shared__ float s_b1[HID];
    __shared__ float s_wl[HID];
    for (int i = threadIdx.x; i < HID * HID; i += 256) s_w1[i / HID][i % HID] = w1[i];
    if (threadIdx.x < HID) { s_b1[threadIdx.x] = b1[threadIdx.x]; s_wl[threadIdx.x] = wl[threadIdx.x]; }
    __syncthreads();
    const int e = blockIdx.x * 256 + threadIdx.x;
    if (e >= n) return;

    const __half* hbase = xpbuf + ((size_t)e * ROWSP + (T_STEPS - 1)) * GATES;
    alignas(16) __half hx[HID];
    const uint4* hr = reinterpret_cast<const uint4*>(hbase);
    #pragma unroll
    for (int q = 0; q < HID / 8; ++q) reinterpret_cast<uint4*>(hx)[q] = hr[q];
    float h[HID];
    #pragma unroll
    for (int k = 0; k < HID; ++k) h[k] = __half2float(hx[k]);

    float acc = bl[0];
    #pragma unroll
    for (int u = 0; u < HID; ++u) {
        float a = s_b1[u];
        #pragma unroll
        for (int d = 0; d < HID; ++d) a += s_w1[u][d] * h[d];
        a = a > 0.f ? a : 0.01f * a;
        acc += a * s_wl[u];
    }
    outp[e] = 1.f / (1.f + __expf(-acc));
}

extern "C" void kernel_launch(void* const* d_in, const int* in_sizes, int n_in,
                              void* d_out, int out_size, void* d_ws, size_t ws_size,
                              hipStream_t stream)
{
    const float* x      = (const float*)d_in[0];
    const float* g0_wih = (const float*)d_in[1];
    const float* g0_whh = (const float*)d_in[2];
    const float* g0_bih = (const float*)d_in[3];
    const float* g0_bhh = (const float*)d_in[4];
    const float* g_wih  = (const float*)d_in[5];   // [4,120,40]
    const float* g_whh  = (const float*)d_in[6];   // [4,120,40]
    const float* g_bih  = (const float*)d_in[7];   // [4,120]
    const float* g_bhh  = (const float*)d_in[8];   // [4,120]
    const float* mlp_w1 = (const float*)d_in[9];   // [4,40,40]
    const float* mlp_b1 = (const float*)d_in[10];  // [4,40]
    const float* mlp_w2 = (const float*)d_in[11];  // [3,40,40]
    const float* mlp_b2 = (const float*)d_in[12];  // [3,40]
    const float* w_last = (const float*)d_in[13];  // [1,40]
    const float* b_last = (const float*)d_in[14];  // [1]

    const int B = in_sizes[0] / (T_STEPS * 20);
    float* out = (float*)d_out;

    // ws (halfs): [w1pad 3*3072][effpad 3*8192][g0pad 4096][g1pad 8192][pad 24000] then xp
    __half* wsz    = (__half*)d_ws;
    __half* w1pad  = wsz;                       // 9216
    __half* effpad = wsz + 3 * 3072;            // 24576
    __half* g0pad  = wsz + 9216 + 3 * 8192;     // 4096
    __half* g1pad  = g0pad + 4096;              // 8192
    _Float16* xpbuf = (_Float16*)(wsz + 70080); // same layout as R16/17 (region before unused now)
    const size_t ws_rem = ws_size - 70080 * sizeof(__half);

    for (int li = 0; li < 3; ++li)
        prep_pad<<<dim3(12), dim3(256), 0, stream>>>(
            mlp_w1 + li * 1600, mlp_b1 + li * 40, w1pad + li * 3072, 40, 40, 64);
    prep_pad<<<dim3(16), dim3(256), 0, stream>>>(g0_wih, g0_bih, g0pad, 120, 20, 32);
    prep_pad<<<dim3(32), dim3(256), 0, stream>>>(g_wih, g_bih, g1pad, 120, 40, 64);
    prep_eff<<<dim3(32, 3), dim3(256), 0, stream>>>(g_wih, g_bih, mlp_w2, mlp_b2, effpad);

    const size_t per_e = (size_t)ROWSP * GATES * sizeof(__half);  // padded element footprint
    int CB = B;
    while ((size_t)CB * per_e > ws_rem && CB > 64) CB >>= 1;

    for (int c = 0; c < B; c += CB) {
        const int  nrows = CB * T_STEPS;
        const dim3 pgrd(nrows / 512), pblk(256);
        const dim3 rgrd(CB), rblk(64);
        const float* xc = x + (size_t)c * T_STEPS * 20;

        precomp_mfma<0><<<pgrd, pblk, 0, stream>>>(
            xc, xpbuf, (const _Float16*)g0pad, nullptr, nrows);
        gru_recS<<<rgrd, rblk, 0, stream>>>((__half*)xpbuf, g0_whh, g0_bhh);

        precomp_mfma<1><<<pgrd, pblk, 0, stream>>>(
            xpbuf, xpbuf, (const _Float16*)g1pad, nullptr, nrows);
        gru_recS<<<rgrd, rblk, 0, stream>>>((__half*)xpbuf, g_whh + 0 * 4800, g_bhh + 0 * 120);

        for (int li = 0; li < 3; ++li) {
            precomp_mfma<2><<<pgrd, pblk, 0, stream>>>(
                xpbuf, xpbuf, (const _Float16*)(effpad + li * 8192),
                (const _Float16*)(w1pad + li * 3072), nrows);
            gru_recS<<<rgrd, rblk, 0, stream>>>(
                (__half*)xpbuf, g_whh + (li + 1) * 4800, g_bhh + (li + 1) * 120);
        }

        final_head<<<dim3((CB + 255) / 256), dim3(256), 0, stream>>>(
            (const __half*)xpbuf, out + c,
            mlp_w1 + 3 * 1600, mlp_b1 + 3 * 40, w_last, b_last, CB);
    }
}

// Round 20
// 2031.471 us; speedup vs baseline: 1.0715x; 1.0715x over previous
//
#include <hip/hip_runtime.h>
#include <hip/hip_fp16.h>
#include <cstdint>
#include <cstddef>

#define T_STEPS 512
#define ROWSP   516          // padded rows per element (3-deep unconditional prefetch)
#define HID 40
#define GATES 120

typedef _Float16 half8 __attribute__((ext_vector_type(8)));
typedef _Float16 fp16x2 __attribute__((ext_vector_type(2)));
typedef float f32x4 __attribute__((ext_vector_type(4)));

__device__ __forceinline__ void wavesync() { asm volatile("s_waitcnt lgkmcnt(0)" ::: "memory"); }
__device__ __forceinline__ float sigm(float x) { return 1.f / (1.f + __expf(-x)); }

template<int J>
__device__ __forceinline__ fp16x2 ext2(half8 v) {
    return __builtin_shufflevector(v, v, 2 * J, 2 * J + 1);
}

// Guaranteed single-instruction dot: v_dot2_f32_f16 d, a, b, c
__device__ __forceinline__ float vdot2(fp16x2 a, fp16x2 b, float c) {
    float d;
    asm("v_dot2_f32_f16 %0, %1, %2, %3" : "=v"(d) : "v"(a), "v"(b), "v"(c));
    return d;
}

// padded-row byte mapping: row i (linear e*512+t) lives at (e*516+t)*GATES
__device__ __forceinline__ size_t rowoff(int row) {
    return ((size_t)(row >> 9) * ROWSP + (row & 511)) * GATES;
}

// ---------------- weight prep (run once, tiny) ----------------
__global__ __launch_bounds__(256) void prep_pad(
    const float* __restrict__ w, const float* __restrict__ b,
    __half* __restrict__ out, int N, int K, int KPAD)
{
    const int idx = blockIdx.x * 256 + threadIdx.x;
    const int n = idx / KPAD, k = idx - n * KPAD;
    float v = 0.f;
    if (n < N) {
        if (k < K) v = w[n * K + k];
        else if (k == KPAD - 1) v = b[n];
    }
    out[idx] = __float2half(v);
}

__global__ __launch_bounds__(256) void prep_eff(
    const float* __restrict__ g_wih, const float* __restrict__ g_bih,
    const float* __restrict__ w2, const float* __restrict__ b2,
    __half* __restrict__ out)
{
    const int li  = blockIdx.y;
    const int idx = blockIdx.x * 256 + threadIdx.x;   // over 128*64
    const int n = idx >> 6, k = idx & 63;
    float v = 0.f;
    if (n < GATES) {
        const float* wrow = g_wih + ((size_t)(li + 1) * GATES + n) * HID;
        if (k < HID) {
            for (int j = 0; j < HID; ++j) v += wrow[j] * w2[((size_t)li * HID + j) * HID + k];
        } else if (k == 63) {
            v = g_bih[(size_t)(li + 1) * GATES + n];
            for (int j = 0; j < HID; ++j) v += wrow[j] * b2[(size_t)li * HID + j];
        }
    }
    out[(size_t)li * 128 * 64 + idx] = __float2half(v);
}

__global__ __launch_bounds__(256) void prep_f16cvt(
    const float* __restrict__ w, _Float16* __restrict__ o, int n)
{
    const int i = blockIdx.x * 256 + threadIdx.x;
    if (i < n) o[i] = (_Float16)w[i];
}

// ---------------- MFMA gate precompute (R7-verified; padded-row addressing) ----------------
template<int MODE>
__global__ __launch_bounds__(256) void precomp_mfma(
    const void* in_, _Float16* xp,
    const _Float16* __restrict__ wihpad,  // [128][KP]
    const _Float16* __restrict__ w1pad,   // [48][64] (MODE 2 only)
    int nrows)
{
    __shared__ _Float16 s_v[4][1024];     // per-wave 2KB swizzled V tile [16][64]
    const int tid  = threadIdx.x;
    const int wid  = tid >> 6, lane = tid & 63;
    const int g    = lane >> 4, r = lane & 15;

    constexpr int KP  = (MODE == 0) ? 32 : 64;
    constexpr int NKS = KP / 32;

    half8 bw[8][NKS];
    #pragma unroll
    for (int t = 0; t < 8; ++t)
        #pragma unroll
        for (int ks = 0; ks < NKS; ++ks)
            bw[t][ks] = *reinterpret_cast<const half8*>(wihpad + (t * 16 + r) * KP + ks * 32 + g * 8);

    half8 b1f[3][2];
    char* myv = nullptr;
    if constexpr (MODE == 2) {
        #pragma unroll
        for (int t = 0; t < 3; ++t)
            #pragma unroll
            for (int ks = 0; ks < 2; ++ks)
                b1f[t][ks] = *reinterpret_cast<const half8*>(w1pad + (t * 16 + r) * 64 + ks * 32 + g * 8);
        myv = (char*)&s_v[wid][0];
        uint4 z; z.x = z.y = z.z = z.w = 0u;
        *reinterpret_cast<uint4*>(myv + lane * 32)      = z;
        *reinterpret_cast<uint4*>(myv + lane * 32 + 16) = z;
        wavesync();
        if (lane < 16)
            *reinterpret_cast<_Float16*>(myv + lane * 128 + (126 ^ ((lane & 7) << 4))) = (_Float16)1.f;
        wavesync();
    }

    const int w0     = blockIdx.x * 4 + wid;
    const int stride = gridDim.x * 64;

    for (int rb = w0 * 16; rb < nrows; rb += stride) {
        half8 a0, a1;
        if constexpr (MODE == 0) {
            const float* xr = (const float*)in_ + (size_t)(rb + r) * 20;
            if (g < 2) {
                const float4 v0 = *reinterpret_cast<const float4*>(xr + g * 8);
                const float4 v1 = *reinterpret_cast<const float4*>(xr + g * 8 + 4);
                a0[0]=(_Float16)v0.x; a0[1]=(_Float16)v0.y; a0[2]=(_Float16)v0.z; a0[3]=(_Float16)v0.w;
                a0[4]=(_Float16)v1.x; a0[5]=(_Float16)v1.y; a0[6]=(_Float16)v1.z; a0[7]=(_Float16)v1.w;
            } else if (g == 2) {
                const float4 v0 = *reinterpret_cast<const float4*>(xr + 16);
                a0[0]=(_Float16)v0.x; a0[1]=(_Float16)v0.y; a0[2]=(_Float16)v0.z; a0[3]=(_Float16)v0.w;
                a0[4]=(_Float16)0.f; a0[5]=(_Float16)0.f; a0[6]=(_Float16)0.f; a0[7]=(_Float16)0.f;
            } else {
                #pragma unroll
                for (int j = 0; j < 8; ++j) a0[j] = (_Float16)0.f;
                a0[7] = (_Float16)1.f;    // bias slot k=31
            }
        } else {
            const _Float16* hr = (const _Float16*)in_ + rowoff(rb + r);
            a0 = *reinterpret_cast<const half8*>(hr + g * 8);          // k 0..31
            if (g == 0) {
                a1 = *reinterpret_cast<const half8*>(hr + 32);         // k 32..39
            } else {
                #pragma unroll
                for (int j = 0; j < 8; ++j) a1[j] = (_Float16)0.f;
                if (g == 3) a1[7] = (_Float16)1.f;                     // bias slot k=63
            }
        }

        if constexpr (MODE == 2) {
            #pragma unroll
            for (int t = 0; t < 3; ++t) {
                f32x4 acc = {0.f, 0.f, 0.f, 0.f};
                acc = __builtin_amdgcn_mfma_f32_16x16x32_f16(a0, b1f[t][0], acc, 0, 0, 0);
                acc = __builtin_amdgcn_mfma_f32_16x16x32_f16(a1, b1f[t][1], acc, 0, 0, 0);
                const int n2 = (t * 16 + r) * 2;                       // byte col
                #pragma unroll
                for (int reg = 0; reg < 4; ++reg) {
                    const int m = g * 4 + reg;
                    float v = acc[reg];
                    v = v > 0.f ? v : 0.01f * v;
                    *reinterpret_cast<_Float16*>(myv + m * 128 + (n2 ^ ((m & 7) << 4))) = (_Float16)v;
                }
            }
            wavesync();
            const int sw = (r & 7) << 4;
            a0 = *reinterpret_cast<const half8*>(myv + r * 128 + ((g * 16) ^ sw));
            a1 = *reinterpret_cast<const half8*>(myv + r * 128 + ((64 + g * 16) ^ sw));
        }

        #pragma unroll
        for (int t = 0; t < 8; ++t) {
            f32x4 acc = {0.f, 0.f, 0.f, 0.f};
            acc = __builtin_amdgcn_mfma_f32_16x16x32_f16(a0, bw[t][0], acc, 0, 0, 0);
            if constexpr (NKS == 2)
                acc = __builtin_amdgcn_mfma_f32_16x16x32_f16(a1, bw[t][1], acc, 0, 0, 0);
            const int n = t * 16 + r;
            if (n < GATES) {
                #pragma unroll
                for (int reg = 0; reg < 4; ++reg) {
                    const int m = g * 4 + reg;
                    xp[rowoff(rb + m) + n] = (_Float16)acc[reg];
                }
            }
        }
    }
}

// ---------------- recurrence: 3 gates per lane, ZERO cross-lane ops ----------------
// Lane u (<40) computes ALL its unit's gates: r=u, z=40+u, n=80+u (60 vdot2,
// 12 independent chains). No ds_bpermute — the step's serial chain is just
// ds_read(h) -> dots -> sigmoid/tanh -> h. Weights f16 LDS-staged -> 60 resident
// VGPR dwords (R16-proven pinning: waves_per_eu budget + loop wavesync clobber).
__global__ __launch_bounds__(64)
__attribute__((amdgpu_waves_per_eu(2, 2)))
void gru_rec3(
    __half* __restrict__ xp,            // [CB, ROWSP, 120], h written into [t][0:40]
    const _Float16* __restrict__ whh16, // [120][40] f16
    const float* __restrict__ bhh)      // [120]
{
    __shared__ __align__(16) _Float16 s_w[GATES * HID];  // 9600 B staging
    __shared__ __align__(16) _Float16 s_h[64];

    const int lane = threadIdx.x;
    const int e    = blockIdx.x;

    for (int idx = lane; idx < (GATES * HID) / 8; idx += 64)
        reinterpret_cast<uint4*>(s_w)[idx] = reinterpret_cast<const uint4*>(whh16)[idx];

    const int u = (lane < HID) ? lane : 0;    // unit owned by this lane
    const float bhR = bhh[u], bhZ = bhh[40 + u], bhN = bhh[80 + u];

    __half* xpb = xp + (size_t)e * ROWSP * GATES;

    float hreg = 0.f;
    s_h[lane] = (_Float16)0.f;
    wavesync();   // staging + init complete

    // pull this lane's 3 weight rows from LDS into registers (60 dwords)
    fp16x2 wR[20], wZ[20], wN[20];
    {
        const _Float16* rR = s_w + u * HID;
        const _Float16* rZ = s_w + (40 + u) * HID;
        const _Float16* rN = s_w + (80 + u) * HID;
        #pragma unroll
        for (int k = 0; k < 5; ++k) {
            const half8 vR = *reinterpret_cast<const half8*>(rR + k * 8);
            const half8 vZ = *reinterpret_cast<const half8*>(rZ + k * 8);
            const half8 vN = *reinterpret_cast<const half8*>(rN + k * 8);
            wR[4*k+0] = ext2<0>(vR); wZ[4*k+0] = ext2<0>(vZ); wN[4*k+0] = ext2<0>(vN);
            wR[4*k+1] = ext2<1>(vR); wZ[4*k+1] = ext2<1>(vZ); wN[4*k+1] = ext2<1>(vN);
            wR[4*k+2] = ext2<2>(vR); wZ[4*k+2] = ext2<2>(vZ); wN[4*k+2] = ext2<2>(vN);
            wR[4*k+3] = ext2<3>(vR); wZ[4*k+3] = ext2<3>(vZ); wN[4*k+3] = ext2<3>(vN);
        }
    }
    wavesync();

    // 3-deep prefetch of this lane's 3 gate streams, pointer-bumped, unconditional
    __half r0 = xpb[u],             z0 = xpb[40 + u],             n0 = xpb[80 + u];
    __half r1 = xpb[GATES + u],     z1 = xpb[GATES + 40 + u],     n1 = xpb[GATES + 80 + u];
    __half r2 = xpb[2 * GATES + u], z2 = xpb[2 * GATES + 40 + u], n2 = xpb[2 * GATES + 80 + u];
    const __half* pfR = xpb + 3 * GATES + u;
    const __half* pfZ = pfR + 40;
    const __half* pfN = pfR + 80;
    __half*       pst = xpb + lane;

    #pragma unroll 2
    for (int t = 0; t < T_STEPS; ++t) {
        const __half r3 = *pfR;  pfR += GATES;
        const __half z3 = *pfZ;  pfZ += GATES;
        const __half n3 = *pfN;  pfN += GATES;

        const half8 p0 = *reinterpret_cast<const half8*>(&s_h[0]);
        const half8 p1 = *reinterpret_cast<const half8*>(&s_h[8]);
        const half8 p2 = *reinterpret_cast<const half8*>(&s_h[16]);
        const half8 p3 = *reinterpret_cast<const half8*>(&s_h[24]);
        const half8 p4 = *reinterpret_cast<const half8*>(&s_h[32]);

        float R0=0.f, R1=0.f, R2=0.f, R3=0.f;
        float Z0=0.f, Z1=0.f, Z2=0.f, Z3=0.f;
        float N0=0.f, N1=0.f, N2=0.f, N3=0.f;
        R0 = vdot2(ext2<0>(p0), wR[ 0], R0); Z0 = vdot2(ext2<0>(p0), wZ[ 0], Z0); N0 = vdot2(ext2<0>(p0), wN[ 0], N0);
        R1 = vdot2(ext2<1>(p0), wR[ 1], R1); Z1 = vdot2(ext2<1>(p0), wZ[ 1], Z1); N1 = vdot2(ext2<1>(p0), wN[ 1], N1);
        R2 = vdot2(ext2<2>(p0), wR[ 2], R2); Z2 = vdot2(ext2<2>(p0), wZ[ 2], Z2); N2 = vdot2(ext2<2>(p0), wN[ 2], N2);
        R3 = vdot2(ext2<3>(p0), wR[ 3], R3); Z3 = vdot2(ext2<3>(p0), wZ[ 3], Z3); N3 = vdot2(ext2<3>(p0), wN[ 3], N3);
        R0 = vdot2(ext2<0>(p1), wR[ 4], R0); Z0 = vdot2(ext2<0>(p1), wZ[ 4], Z0); N0 = vdot2(ext2<0>(p1), wN[ 4], N0);
        R1 = vdot2(ext2<1>(p1), wR[ 5], R1); Z1 = vdot2(ext2<1>(p1), wZ[ 5], Z1); N1 = vdot2(ext2<1>(p1), wN[ 5], N1);
        R2 = vdot2(ext2<2>(p1), wR[ 6], R2); Z2 = vdot2(ext2<2>(p1), wZ[ 6], Z2); N2 = vdot2(ext2<2>(p1), wN[ 6], N2);
        R3 = vdot2(ext2<3>(p1), wR[ 7], R3); Z3 = vdot2(ext2<3>(p1), wZ[ 7], Z3); N3 = vdot2(ext2<3>(p1), wN[ 7], N3);
        R0 = vdot2(ext2<0>(p2), wR[ 8], R0); Z0 = vdot2(ext2<0>(p2), wZ[ 8], Z0); N0 = vdot2(ext2<0>(p2), wN[ 8], N0);
        R1 = vdot2(ext2<1>(p2), wR[ 9], R1); Z1 = vdot2(ext2<1>(p2), wZ[ 9], Z1); N1 = vdot2(ext2<1>(p2), wN[ 9], N1);
        R2 = vdot2(ext2<2>(p2), wR[10], R2); Z2 = vdot2(ext2<2>(p2), wZ[10], Z2); N2 = vdot2(ext2<2>(p2), wN[10], N2);
        R3 = vdot2(ext2<3>(p2), wR[11], R3); Z3 = vdot2(ext2<3>(p2), wZ[11], Z3); N3 = vdot2(ext2<3>(p2), wN[11], N3);
        R0 = vdot2(ext2<0>(p3), wR[12], R0); Z0 = vdot2(ext2<0>(p3), wZ[12], Z0); N0 = vdot2(ext2<0>(p3), wN[12], N0);
        R1 = vdot2(ext2<1>(p3), wR[13], R1); Z1 = vdot2(ext2<1>(p3), wZ[13], Z1); N1 = vdot2(ext2<1>(p3), wN[13], N1);
        R2 = vdot2(ext2<2>(p3), wR[14], R2); Z2 = vdot2(ext2<2>(p3), wZ[14], Z2); N2 = vdot2(ext2<2>(p3), wN[14], N2);
        R3 = vdot2(ext2<3>(p3), wR[15], R3); Z3 = vdot2(ext2<3>(p3), wZ[15], Z3); N3 = vdot2(ext2<3>(p3), wN[15], N3);
        R0 = vdot2(ext2<0>(p4), wR[16], R0); Z0 = vdot2(ext2<0>(p4), wZ[16], Z0); N0 = vdot2(ext2<0>(p4), wN[16], N0);
        R1 = vdot2(ext2<1>(p4), wR[17], R1); Z1 = vdot2(ext2<1>(p4), wZ[17], Z1); N1 = vdot2(ext2<1>(p4), wN[17], N1);
        R2 = vdot2(ext2<2>(p4), wR[18], R2); Z2 = vdot2(ext2<2>(p4), wZ[18], Z2); N2 = vdot2(ext2<2>(p4), wN[18], N2);
        R3 = vdot2(ext2<3>(p4), wR[19], R3); Z3 = vdot2(ext2<3>(p4), wZ[19], Z3); N3 = vdot2(ext2<3>(p4), wN[19], N3);

        const float shR = bhR + ((R0 + R2) + (R1 + R3));
        const float shZ = bhZ + ((Z0 + Z2) + (Z1 + Z3));
        const float shN = bhN + ((N0 + N2) + (N1 + N3));
        const float sumR = __half2float(r0) + shR;
        const float sumZ = __half2float(z0) + shZ;

        const float rr  = sigm(sumR);
        const float zz  = sigm(sumZ);
        const float pre = __half2float(n0) + rr * shN;   // x_n + r*h_n (biases incl.)
        const float ex  = __expf(-2.f * pre);
        const float nn  = (1.f - ex) / (1.f + ex);
        hreg = (1.f - zz) * nn + zz * hreg;
        s_h[lane] = (_Float16)hreg;       // lanes>=40 write unread slots
        if (lane < HID) *pst = __float2half(hreg);
        pst += GATES;

        r0 = r1; z0 = z1; n0 = n1;
        r1 = r2; z1 = z2; n1 = n2;
        r2 = r3; z2 = z3; n2 = n3;
        wavesync();   // s_h ordered for next step; clobber pins weights in regs
    }
}

// ---------------- head ----------------
__global__ __launch_bounds__(256) void final_head(
    const __half* __restrict__ xpbuf,  // padded buffer base
    float* __restrict__ outp,          // [CB]
    const float* __restrict__ w1, const float* __restrict__ b1,
    const float* __restrict__ wl, const float* __restrict__ bl, int n)
{
    __shared__ float s_w1[HID][HID + 1];
    __shared__ float s_b1[HID];
    __shared__ float s_wl[HID];
    for (int i = threadIdx.x; i < HID * HID; i += 256) s_w1[i / HID][i % HID] = w1[i];
    if (threadIdx.x < HID) { s_b1[threadIdx.x] = b1[threadIdx.x]; s_wl[threadIdx.x] = wl[threadIdx.x]; }
    __syncthreads();
    const int e = blockIdx.x * 256 + threadIdx.x;
    if (e >= n) return;

    const __half* hbase = xpbuf + ((size_t)e * ROWSP + (T_STEPS - 1)) * GATES;
    alignas(16) __half hx[HID];
    const uint4* hr = reinterpret_cast<const uint4*>(hbase);
    #pragma unroll
    for (int q = 0; q < HID / 8; ++q) reinterpret_cast<uint4*>(hx)[q] = hr[q];
    float h[HID];
    #pragma unroll
    for (int k = 0; k < HID; ++k) h[k] = __half2float(hx[k]);

    float acc = bl[0];
    #pragma unroll
    for (int u = 0; u < HID; ++u) {
        float a = s_b1[u];
        #pragma unroll
        for (int d = 0; d < HID; ++d) a += s_w1[u][d] * h[d];
        a = a > 0.f ? a : 0.01f * a;
        acc += a * s_wl[u];
    }
    outp[e] = 1.f / (1.f + __expf(-acc));
}

extern "C" void kernel_launch(void* const* d_in, const int* in_sizes, int n_in,
                              void* d_out, int out_size, void* d_ws, size_t ws_size,
                              hipStream_t stream)
{
    const float* x      = (const float*)d_in[0];
    const float* g0_wih = (const float*)d_in[1];
    const float* g0_whh = (const float*)d_in[2];
    const float* g0_bih = (const float*)d_in[3];
    const float* g0_bhh = (const float*)d_in[4];
    const float* g_wih  = (const float*)d_in[5];   // [4,120,40]
    const float* g_whh  = (const float*)d_in[6];   // [4,120,40]
    const float* g_bih  = (const float*)d_in[7];   // [4,120]
    const float* g_bhh  = (const float*)d_in[8];   // [4,120]
    const float* mlp_w1 = (const float*)d_in[9];   // [4,40,40]
    const float* mlp_b1 = (const float*)d_in[10];  // [4,40]
    const float* mlp_w2 = (const float*)d_in[11];  // [3,40,40]
    const float* mlp_b2 = (const float*)d_in[12];  // [3,40]
    const float* w_last = (const float*)d_in[13];  // [1,40]
    const float* b_last = (const float*)d_in[14];  // [1]

    const int B = in_sizes[0] / (T_STEPS * 20);
    float* out = (float*)d_out;

    // ws (halfs): [w1pad 3*3072][effpad 3*8192][g0pad 4096][g1pad 8192][whh16 5*4800] then xp
    __half* wsz    = (__half*)d_ws;
    __half* w1pad  = wsz;                       // 9216
    __half* effpad = wsz + 3 * 3072;            // 24576
    __half* g0pad  = wsz + 9216 + 3 * 8192;     // 4096
    __half* g1pad  = g0pad + 4096;              // 8192
    _Float16* whh16 = (_Float16*)(wsz + 46080); // 24000
    _Float16* xpbuf = (_Float16*)(wsz + 70080); // 140160 B of weights, 16B aligned
    const size_t ws_rem = ws_size - 70080 * sizeof(__half);

    for (int li = 0; li < 3; ++li)
        prep_pad<<<dim3(12), dim3(256), 0, stream>>>(
            mlp_w1 + li * 1600, mlp_b1 + li * 40, w1pad + li * 3072, 40, 40, 64);
    prep_pad<<<dim3(16), dim3(256), 0, stream>>>(g0_wih, g0_bih, g0pad, 120, 20, 32);
    prep_pad<<<dim3(32), dim3(256), 0, stream>>>(g_wih, g_bih, g1pad, 120, 40, 64);
    prep_eff<<<dim3(32, 3), dim3(256), 0, stream>>>(g_wih, g_bih, mlp_w2, mlp_b2, effpad);
    prep_f16cvt<<<dim3(19), dim3(256), 0, stream>>>(g0_whh, whh16, 4800);
    prep_f16cvt<<<dim3(75), dim3(256), 0, stream>>>(g_whh, whh16 + 4800, 19200);

    const size_t per_e = (size_t)ROWSP * GATES * sizeof(__half);  // padded element footprint
    int CB = B;
    while ((size_t)CB * per_e > ws_rem && CB > 64) CB >>= 1;

    for (int c = 0; c < B; c += CB) {
        const int  nrows = CB * T_STEPS;
        const dim3 pgrd(nrows / 512), pblk(256);
        const dim3 rgrd(CB), rblk(64);
        const float* xc = x + (size_t)c * T_STEPS * 20;

        precomp_mfma<0><<<pgrd, pblk, 0, stream>>>(
            xc, xpbuf, (const _Float16*)g0pad, nullptr, nrows);
        gru_rec3<<<rgrd, rblk, 0, stream>>>((__half*)xpbuf, whh16, g0_bhh);

        precomp_mfma<1><<<pgrd, pblk, 0, stream>>>(
            xpbuf, xpbuf, (const _Float16*)g1pad, nullptr, nrows);
        gru_rec3<<<rgrd, rblk, 0, stream>>>((__half*)xpbuf, whh16 + 4800, g_bhh + 0 * 120);

        for (int li = 0; li < 3; ++li) {
            precomp_mfma<2><<<pgrd, pblk, 0, stream>>>(
                xpbuf, xpbuf, (const _Float16*)(effpad + li * 8192),
                (const _Float16*)(w1pad + li * 3072), nrows);
            gru_rec3<<<rgrd, rblk, 0, stream>>>(
                (__half*)xpbuf, whh16 + 4800 + (li + 1) * 4800, g_bhh + (li + 1) * 120);
        }

        final_head<<<dim3((CB + 255) / 256), dim3(256), 0, stream>>>(
            (const __half*)xpbuf, out + c,
            mlp_w1 + 3 * 1600, mlp_b1 + 3 * 40, w_last, b_last, CB);
    }
}

// Round 21
// 1739.499 us; speedup vs baseline: 1.2513x; 1.1678x over previous
//
#include <hip/hip_runtime.h>
#include <hip/hip_fp16.h>
#include <cstdint>
#include <cstddef>

#define T_STEPS 512
#define ROWSP   516          // padded rows per element (3-deep unconditional prefetch)
#define HID 40
#define GATES 120

typedef _Float16 half8 __attribute__((ext_vector_type(8)));
typedef _Float16 fp16x2 __attribute__((ext_vector_type(2)));
typedef float f32x4 __attribute__((ext_vector_type(4)));

__device__ __forceinline__ void wavesync() { asm volatile("s_waitcnt lgkmcnt(0)" ::: "memory"); }
__device__ __forceinline__ float bperm(int srclane, float v) {
    return __int_as_float(__builtin_amdgcn_ds_bpermute(srclane << 2, __float_as_int(v)));
}

#define LOG2E 1.44269504088896f
// sigmoid/tanh via hw exp2 (v_exp_f32): minimal instruction expansion
__device__ __forceinline__ float sigm2(float x) {
    return 1.f / (1.f + __builtin_exp2f(-LOG2E * x));
}
__device__ __forceinline__ float tanh2(float x) {
    const float ex = __builtin_exp2f(-2.f * LOG2E * x);
    return (1.f - ex) / (1.f + ex);
}

template<int J>
__device__ __forceinline__ fp16x2 ext2(half8 v) {
    return __builtin_shufflevector(v, v, 2 * J, 2 * J + 1);
}

// Guaranteed single-instruction dot: v_dot2_f32_f16 d, a, b, c
__device__ __forceinline__ float vdot2(fp16x2 a, fp16x2 b, float c) {
    float d;
    asm("v_dot2_f32_f16 %0, %1, %2, %3" : "=v"(d) : "v"(a), "v"(b), "v"(c));
    return d;
}

// padded-row byte mapping: row i (linear e*512+t) lives at (e*516+t)*GATES
__device__ __forceinline__ size_t rowoff(int row) {
    return ((size_t)(row >> 9) * ROWSP + (row & 511)) * GATES;
}

// ---------------- weight prep (run once, tiny) ----------------
__global__ __launch_bounds__(256) void prep_pad(
    const float* __restrict__ w, const float* __restrict__ b,
    __half* __restrict__ out, int N, int K, int KPAD)
{
    const int idx = blockIdx.x * 256 + threadIdx.x;
    const int n = idx / KPAD, k = idx - n * KPAD;
    float v = 0.f;
    if (n < N) {
        if (k < K) v = w[n * K + k];
        else if (k == KPAD - 1) v = b[n];
    }
    out[idx] = __float2half(v);
}

__global__ __launch_bounds__(256) void prep_eff(
    const float* __restrict__ g_wih, const float* __restrict__ g_bih,
    const float* __restrict__ w2, const float* __restrict__ b2,
    __half* __restrict__ out)
{
    const int li  = blockIdx.y;
    const int idx = blockIdx.x * 256 + threadIdx.x;   // over 128*64
    const int n = idx >> 6, k = idx & 63;
    float v = 0.f;
    if (n < GATES) {
        const float* wrow = g_wih + ((size_t)(li + 1) * GATES + n) * HID;
        if (k < HID) {
            for (int j = 0; j < HID; ++j) v += wrow[j] * w2[((size_t)li * HID + j) * HID + k];
        } else if (k == 63) {
            v = g_bih[(size_t)(li + 1) * GATES + n];
            for (int j = 0; j < HID; ++j) v += wrow[j] * b2[(size_t)li * HID + j];
        }
    }
    out[(size_t)li * 128 * 64 + idx] = __float2half(v);
}

__global__ __launch_bounds__(256) void prep_f16cvt(
    const float* __restrict__ w, _Float16* __restrict__ o, int n)
{
    const int i = blockIdx.x * 256 + threadIdx.x;
    if (i < n) o[i] = (_Float16)w[i];
}

// ---------------- MFMA gate precompute (R7-verified; padded-row addressing) ----------------
template<int MODE>
__global__ __launch_bounds__(256) void precomp_mfma(
    const void* in_, _Float16* xp,
    const _Float16* __restrict__ wihpad,  // [128][KP]
    const _Float16* __restrict__ w1pad,   // [48][64] (MODE 2 only)
    int nrows)
{
    __shared__ _Float16 s_v[4][1024];     // per-wave 2KB swizzled V tile [16][64]
    const int tid  = threadIdx.x;
    const int wid  = tid >> 6, lane = tid & 63;
    const int g    = lane >> 4, r = lane & 15;

    constexpr int KP  = (MODE == 0) ? 32 : 64;
    constexpr int NKS = KP / 32;

    half8 bw[8][NKS];
    #pragma unroll
    for (int t = 0; t < 8; ++t)
        #pragma unroll
        for (int ks = 0; ks < NKS; ++ks)
            bw[t][ks] = *reinterpret_cast<const half8*>(wihpad + (t * 16 + r) * KP + ks * 32 + g * 8);

    half8 b1f[3][2];
    char* myv = nullptr;
    if constexpr (MODE == 2) {
        #pragma unroll
        for (int t = 0; t < 3; ++t)
            #pragma unroll
            for (int ks = 0; ks < 2; ++ks)
                b1f[t][ks] = *reinterpret_cast<const half8*>(w1pad + (t * 16 + r) * 64 + ks * 32 + g * 8);
        myv = (char*)&s_v[wid][0];
        uint4 z; z.x = z.y = z.z = z.w = 0u;
        *reinterpret_cast<uint4*>(myv + lane * 32)      = z;
        *reinterpret_cast<uint4*>(myv + lane * 32 + 16) = z;
        wavesync();
        if (lane < 16)
            *reinterpret_cast<_Float16*>(myv + lane * 128 + (126 ^ ((lane & 7) << 4))) = (_Float16)1.f;
        wavesync();
    }

    const int w0     = blockIdx.x * 4 + wid;
    const int stride = gridDim.x * 64;

    for (int rb = w0 * 16; rb < nrows; rb += stride) {
        half8 a0, a1;
        if constexpr (MODE == 0) {
            const float* xr = (const float*)in_ + (size_t)(rb + r) * 20;
            if (g < 2) {
                const float4 v0 = *reinterpret_cast<const float4*>(xr + g * 8);
                const float4 v1 = *reinterpret_cast<const float4*>(xr + g * 8 + 4);
                a0[0]=(_Float16)v0.x; a0[1]=(_Float16)v0.y; a0[2]=(_Float16)v0.z; a0[3]=(_Float16)v0.w;
                a0[4]=(_Float16)v1.x; a0[5]=(_Float16)v1.y; a0[6]=(_Float16)v1.z; a0[7]=(_Float16)v1.w;
            } else if (g == 2) {
                const float4 v0 = *reinterpret_cast<const float4*>(xr + 16);
                a0[0]=(_Float16)v0.x; a0[1]=(_Float16)v0.y; a0[2]=(_Float16)v0.z; a0[3]=(_Float16)v0.w;
                a0[4]=(_Float16)0.f; a0[5]=(_Float16)0.f; a0[6]=(_Float16)0.f; a0[7]=(_Float16)0.f;
            } else {
                #pragma unroll
                for (int j = 0; j < 8; ++j) a0[j] = (_Float16)0.f;
                a0[7] = (_Float16)1.f;    // bias slot k=31
            }
        } else {
            const _Float16* hr = (const _Float16*)in_ + rowoff(rb + r);
            a0 = *reinterpret_cast<const half8*>(hr + g * 8);          // k 0..31
            if (g == 0) {
                a1 = *reinterpret_cast<const half8*>(hr + 32);         // k 32..39
            } else {
                #pragma unroll
                for (int j = 0; j < 8; ++j) a1[j] = (_Float16)0.f;
                if (g == 3) a1[7] = (_Float16)1.f;                     // bias slot k=63
            }
        }

        if constexpr (MODE == 2) {
            #pragma unroll
            for (int t = 0; t < 3; ++t) {
                f32x4 acc = {0.f, 0.f, 0.f, 0.f};
                acc = __builtin_amdgcn_mfma_f32_16x16x32_f16(a0, b1f[t][0], acc, 0, 0, 0);
                acc = __builtin_amdgcn_mfma_f32_16x16x32_f16(a1, b1f[t][1], acc, 0, 0, 0);
                const int n2 = (t * 16 + r) * 2;                       // byte col
                #pragma unroll
                for (int reg = 0; reg < 4; ++reg) {
                    const int m = g * 4 + reg;
                    float v = acc[reg];
                    v = v > 0.f ? v : 0.01f * v;
                    *reinterpret_cast<_Float16*>(myv + m * 128 + (n2 ^ ((m & 7) << 4))) = (_Float16)v;
                }
            }
            wavesync();
            const int sw = (r & 7) << 4;
            a0 = *reinterpret_cast<const half8*>(myv + r * 128 + ((g * 16) ^ sw));
            a1 = *reinterpret_cast<const half8*>(myv + r * 128 + ((64 + g * 16) ^ sw));
        }

        #pragma unroll
        for (int t = 0; t < 8; ++t) {
            f32x4 acc = {0.f, 0.f, 0.f, 0.f};
            acc = __builtin_amdgcn_mfma_f32_16x16x32_f16(a0, bw[t][0], acc, 0, 0, 0);
            if constexpr (NKS == 2)
                acc = __builtin_amdgcn_mfma_f32_16x16x32_f16(a1, bw[t][1], acc, 0, 0, 0);
            const int n = t * 16 + r;
            if (n < GATES) {
                #pragma unroll
                for (int reg = 0; reg < 4; ++reg) {
                    const int m = g * 4 + reg;
                    xp[rowoff(rb + m) + n] = (_Float16)acc[reg];
                }
            }
        }
    }
}

// ---------------- recurrence: R16 structure + asm vdot2 + exp2 transcendentals ----------------
// Clean composition of proven wins: LDS-staged register weights (R16 pinning:
// waves_per_eu(2,2) budget + loop wavesync clobber), asm v_dot2_f32_f16 (R17:
// 1 instr per 2-MAC), PREDICATED global store (keeps WRITE_SIZE at 98MB; R17's
// all-lane store inflated it 1.5x), exp2-based sigmoid/tanh (2 instr each).
__global__ __launch_bounds__(64)
__attribute__((amdgpu_waves_per_eu(2, 2)))
void gru_recR(
    __half* __restrict__ xp,            // [CB, ROWSP, 120], h written into [t][0:40]
    const _Float16* __restrict__ whh16, // [120][40] f16
    const float* __restrict__ bhh)      // [120]
{
    __shared__ __align__(16) _Float16 s_w[GATES * HID];  // 9600 B staging
    __shared__ __align__(16) _Float16 s_h[64];

    const int lane = threadIdx.x;
    const int e    = blockIdx.x;

    for (int idx = lane; idx < (GATES * HID) / 8; idx += 64)
        reinterpret_cast<uint4*>(s_w)[idx] = reinterpret_cast<const uint4*>(whh16)[idx];

    const int gA = lane;
    const int gB = (lane < 40) ? (80 + lane) : ((lane < 56) ? (24 + lane) : lane);
    const float bhA = bhh[gA], bhB = bhh[gB];

    __half* xpb = xp + (size_t)e * ROWSP * GATES;

    float hreg = 0.f;
    s_h[lane] = (_Float16)0.f;
    wavesync();   // staging + init complete

    // pull this lane's 2 weight rows from LDS into registers (40 dwords)
    fp16x2 wA[20], wB[20];
    {
        const _Float16* wrA = s_w + gA * HID;
        const _Float16* wrB = s_w + gB * HID;
        #pragma unroll
        for (int k = 0; k < 5; ++k) {
            const half8 wa = *reinterpret_cast<const half8*>(wrA + k * 8);
            const half8 wb = *reinterpret_cast<const half8*>(wrB + k * 8);
            wA[4*k+0] = ext2<0>(wa); wB[4*k+0] = ext2<0>(wb);
            wA[4*k+1] = ext2<1>(wa); wB[4*k+1] = ext2<1>(wb);
            wA[4*k+2] = ext2<2>(wa); wB[4*k+2] = ext2<2>(wb);
            wA[4*k+3] = ext2<3>(wa); wB[4*k+3] = ext2<3>(wb);
        }
    }
    wavesync();

    // 3-deep prefetch, pointer-bumped; padded rows make it unconditional
    __half a0 = xpb[gA],             c0 = xpb[gB];
    __half a1 = xpb[GATES + gA],     c1 = xpb[GATES + gB];
    __half a2 = xpb[2 * GATES + gA], c2 = xpb[2 * GATES + gB];
    const __half* pfA = xpb + 3 * GATES + gA;
    const __half* pfB = xpb + 3 * GATES + gB;
    __half*       pst = xpb + lane;

    #pragma unroll 4
    for (int t = 0; t < T_STEPS; ++t) {
        const __half a3 = *pfA;  pfA += GATES;
        const __half c3 = *pfB;  pfB += GATES;

        const half8 p0 = *reinterpret_cast<const half8*>(&s_h[0]);
        const half8 p1 = *reinterpret_cast<const half8*>(&s_h[8]);
        const half8 p2 = *reinterpret_cast<const half8*>(&s_h[16]);
        const half8 p3 = *reinterpret_cast<const half8*>(&s_h[24]);
        const half8 p4 = *reinterpret_cast<const half8*>(&s_h[32]);

        float A0 = 0.f, A1 = 0.f, A2 = 0.f, A3 = 0.f;
        float B0 = 0.f, B1 = 0.f, B2 = 0.f, B3 = 0.f;
        A0 = vdot2(ext2<0>(p0), wA[ 0], A0); B0 = vdot2(ext2<0>(p0), wB[ 0], B0);
        A1 = vdot2(ext2<1>(p0), wA[ 1], A1); B1 = vdot2(ext2<1>(p0), wB[ 1], B1);
        A2 = vdot2(ext2<2>(p0), wA[ 2], A2); B2 = vdot2(ext2<2>(p0), wB[ 2], B2);
        A3 = vdot2(ext2<3>(p0), wA[ 3], A3); B3 = vdot2(ext2<3>(p0), wB[ 3], B3);
        A0 = vdot2(ext2<0>(p1), wA[ 4], A0); B0 = vdot2(ext2<0>(p1), wB[ 4], B0);
        A1 = vdot2(ext2<1>(p1), wA[ 5], A1); B1 = vdot2(ext2<1>(p1), wB[ 5], B1);
        A2 = vdot2(ext2<2>(p1), wA[ 6], A2); B2 = vdot2(ext2<2>(p1), wB[ 6], B2);
        A3 = vdot2(ext2<3>(p1), wA[ 7], A3); B3 = vdot2(ext2<3>(p1), wB[ 7], B3);
        A0 = vdot2(ext2<0>(p2), wA[ 8], A0); B0 = vdot2(ext2<0>(p2), wB[ 8], B0);
        A1 = vdot2(ext2<1>(p2), wA[ 9], A1); B1 = vdot2(ext2<1>(p2), wB[ 9], B1);
        A2 = vdot2(ext2<2>(p2), wA[10], A2); B2 = vdot2(ext2<2>(p2), wB[10], B2);
        A3 = vdot2(ext2<3>(p2), wA[11], A3); B3 = vdot2(ext2<3>(p2), wB[11], B3);
        A0 = vdot2(ext2<0>(p3), wA[12], A0); B0 = vdot2(ext2<0>(p3), wB[12], B0);
        A1 = vdot2(ext2<1>(p3), wA[13], A1); B1 = vdot2(ext2<1>(p3), wB[13], B1);
        A2 = vdot2(ext2<2>(p3), wA[14], A2); B2 = vdot2(ext2<2>(p3), wB[14], B2);
        A3 = vdot2(ext2<3>(p3), wA[15], A3); B3 = vdot2(ext2<3>(p3), wB[15], B3);
        A0 = vdot2(ext2<0>(p4), wA[16], A0); B0 = vdot2(ext2<0>(p4), wB[16], B0);
        A1 = vdot2(ext2<1>(p4), wA[17], A1); B1 = vdot2(ext2<1>(p4), wB[17], B1);
        A2 = vdot2(ext2<2>(p4), wA[18], A2); B2 = vdot2(ext2<2>(p4), wB[18], B2);
        A3 = vdot2(ext2<3>(p4), wA[19], A3); B3 = vdot2(ext2<3>(p4), wB[19], B3);

        const float shA = bhA + ((A0 + A2) + (A1 + A3));
        const float shB = bhB + ((B0 + B2) + (B1 + B3));
        const float xA  = __half2float(a0);
        const float xB  = __half2float(c0);
        const float sumA = xA + shA;
        const float sumB = xB + shB;
        // z_l: lane 40+l (sumA) for l<24, lane 16+l (sumB) for l>=24. All lanes execute.
        const float zA = bperm(40 + lane, sumA);
        const float zB = bperm(16 + lane, sumB);

        // activation branch-free (lanes>=40 garbage, written only to unread s_h slots)
        const float rr  = sigm2(sumA);
        const float z   = sigm2((lane < 24) ? zA : zB);
        const float pre = xB + rr * shB;          // x_n + r*h_n (biases included)
        const float nn  = tanh2(pre);
        hreg = (1.f - z) * nn + z * hreg;
        s_h[lane] = (_Float16)hreg;
        if (lane < HID) *pst = __float2half(hreg);   // predicated: WRITE stays 98MB
        pst += GATES;

        a0 = a1; c0 = c1; a1 = a2; c1 = c2; a2 = a3; c2 = c3;
        wavesync();   // s_h ordered for next step; clobber pins weights in regs
    }
}

// ---------------- head ----------------
__global__ __launch_bounds__(256) void final_head(
    const __half* __restrict__ xpbuf,  // padded buffer base
    float* __restrict__ outp,          // [CB]
    const float* __restrict__ w1, const float* __restrict__ b1,
    const float* __restrict__ wl, const float* __restrict__ bl, int n)
{
    __shared__ float s_w1[HID][HID + 1];
    __shared__ float s_b1[HID];
    __shared__ float s_wl[HID];
    for (int i = threadIdx.x; i < HID * HID; i += 256) s_w1[i / HID][i % HID] = w1[i];
    if (threadIdx.x < HID) { s_b1[threadIdx.x] = b1[threadIdx.x]; s_wl[threadIdx.x] = wl[threadIdx.x]; }
    __syncthreads();
    const int e = blockIdx.x * 256 + threadIdx.x;
    if (e >= n) return;

    const __half* hbase = xpbuf + ((size_t)e * ROWSP + (T_STEPS - 1)) * GATES;
    alignas(16) __half hx[HID];
    const uint4* hr = reinterpret_cast<const uint4*>(hbase);
    #pragma unroll
    for (int q = 0; q < HID / 8; ++q) reinterpret_cast<uint4*>(hx)[q] = hr[q];
    float h[HID];
    #pragma unroll
    for (int k = 0; k < HID; ++k) h[k] = __half2float(hx[k]);

    float acc = bl[0];
    #pragma unroll
    for (int u = 0; u < HID; ++u) {
        float a = s_b1[u];
        #pragma unroll
        for (int d = 0; d < HID; ++d) a += s_w1[u][d] * h[d];
        a = a > 0.f ? a : 0.01f * a;
        acc += a * s_wl[u];
    }
    outp[e] = 1.f / (1.f + __expf(-acc));
}

extern "C" void kernel_launch(void* const* d_in, const int* in_sizes, int n_in,
                              void* d_out, int out_size, void* d_ws, size_t ws_size,
                              hipStream_t stream)
{
    const float* x      = (const float*)d_in[0];
    const float* g0_wih = (const float*)d_in[1];
    const float* g0_whh = (const float*)d_in[2];
    const float* g0_bih = (const float*)d_in[3];
    const float* g0_bhh = (const float*)d_in[4];
    const float* g_wih  = (const float*)d_in[5];   // [4,120,40]
    const float* g_whh  = (const float*)d_in[6];   // [4,120,40]
    const float* g_bih  = (const float*)d_in[7];   // [4,120]
    const float* g_bhh  = (const float*)d_in[8];   // [4,120]
    const float* mlp_w1 = (const float*)d_in[9];   // [4,40,40]
    const float* mlp_b1 = (const float*)d_in[10];  // [4,40]
    const float* mlp_w2 = (const float*)d_in[11];  // [3,40,40]
    const float* mlp_b2 = (const float*)d_in[12];  // [3,40]
    const float* w_last = (const float*)d_in[13];  // [1,40]
    const float* b_last = (const float*)d_in[14];  // [1]

    const int B = in_sizes[0] / (T_STEPS * 20);
    float* out = (float*)d_out;

    // ws (halfs): [w1pad 3*3072][effpad 3*8192][g0pad 4096][g1pad 8192][whh16 5*4800] then xp
    __half* wsz    = (__half*)d_ws;
    __half* w1pad  = wsz;                       // 9216
    __half* effpad = wsz + 3 * 3072;            // 24576
    __half* g0pad  = wsz + 9216 + 3 * 8192;     // 4096
    __half* g1pad  = g0pad + 4096;              // 8192
    _Float16* whh16 = (_Float16*)(wsz + 46080); // 24000
    _Float16* xpbuf = (_Float16*)(wsz + 70080); // 140160 B of weights, 16B aligned
    const size_t ws_rem = ws_size - 70080 * sizeof(__half);

    for (int li = 0; li < 3; ++li)
        prep_pad<<<dim3(12), dim3(256), 0, stream>>>(
            mlp_w1 + li * 1600, mlp_b1 + li * 40, w1pad + li * 3072, 40, 40, 64);
    prep_pad<<<dim3(16), dim3(256), 0, stream>>>(g0_wih, g0_bih, g0pad, 120, 20, 32);
    prep_pad<<<dim3(32), dim3(256), 0, stream>>>(g_wih, g_bih, g1pad, 120, 40, 64);
    prep_eff<<<dim3(32, 3), dim3(256), 0, stream>>>(g_wih, g_bih, mlp_w2, mlp_b2, effpad);
    prep_f16cvt<<<dim3(19), dim3(256), 0, stream>>>(g0_whh, whh16, 4800);
    prep_f16cvt<<<dim3(75), dim3(256), 0, stream>>>(g_whh, whh16 + 4800, 19200);

    const size_t per_e = (size_t)ROWSP * GATES * sizeof(__half);  // padded element footprint
    int CB = B;
    while ((size_t)CB * per_e > ws_rem && CB > 64) CB >>= 1;

    for (int c = 0; c < B; c += CB) {
        const int  nrows = CB * T_STEPS;
        const dim3 pgrd(nrows / 512), pblk(256);
        const dim3 rgrd(CB), rblk(64);
        const float* xc = x + (size_t)c * T_STEPS * 20;

        precomp_mfma<0><<<pgrd, pblk, 0, stream>>>(
            xc, xpbuf, (const _Float16*)g0pad, nullptr, nrows);
        gru_recR<<<rgrd, rblk, 0, stream>>>((__half*)xpbuf, whh16, g0_bhh);

        precomp_mfma<1><<<pgrd, pblk, 0, stream>>>(
            xpbuf, xpbuf, (const _Float16*)g1pad, nullptr, nrows);
        gru_recR<<<rgrd, rblk, 0, stream>>>((__half*)xpbuf, whh16 + 4800, g_bhh + 0 * 120);

        for (int li = 0; li < 3; ++li) {
            precomp_mfma<2><<<pgrd, pblk, 0, stream>>>(
                xpbuf, xpbuf, (const _Float16*)(effpad + li * 8192),
                (const _Float16*)(w1pad + li * 3072), nrows);
            gru_recR<<<rgrd, rblk, 0, stream>>>(
                (__half*)xpbuf, whh16 + 4800 + (li + 1) * 4800, g_bhh + (li + 1) * 120);
        }

        final_head<<<dim3((CB + 255) / 256), dim3(256), 0, stream>>>(
            (const __half*)xpbuf, out + c,
            mlp_w1 + 3 * 1600, mlp_b1 + 3 * 40, w_last, b_last, CB);
    }
}